// Round 4
// baseline (133.174 us; speedup 1.0000x reference)
//
#include <hip/hip_runtime.h>
#include <hip/hip_bf16.h>

typedef __bf16 v8bf16 __attribute__((ext_vector_type(8)));
typedef float  v4f32  __attribute__((ext_vector_type(4)));

#define AS1 __attribute__((address_space(1)))
#define AS3 __attribute__((address_space(3)))

#define CHF 8192          // floats per 64-atom chunk (64*128), 32 KB
#define MAIN_GRID 512     // 2 blocks/CU resident (LDS-limited)

static __device__ __forceinline__ float silu_f(float v) {
    return v / (1.0f + __expf(-v));
}

static __device__ __forceinline__ v8bf16 cvt8(v4f32 f0, v4f32 f1) {
    v8bf16 t;
    t[0] = (__bf16)f0[0]; t[1] = (__bf16)f0[1]; t[2] = (__bf16)f0[2]; t[3] = (__bf16)f0[3];
    t[4] = (__bf16)f1[0]; t[5] = (__bf16)f1[1]; t[6] = (__bf16)f1[2]; t[7] = (__bf16)f1[3];
    return t;
}

__global__ void zero_ws_kernel(float* __restrict__ ws, int n) {
    int i = blockIdx.x * blockDim.x + threadIdx.x;
    if (i < n) ws[i] = 0.0f;
}

// Stage one 64-atom chunk (32 KB of x) into LDS via global_load_lds.
// Each wave stages ONLY its own 16 rows (w*16 .. w*16+15) and later reads
// ONLY those rows -> waves are fully independent, no barriers needed.
// LDS dest linear; global SOURCE carries the inverse of the read-side XOR
// swizzle (rule #21: linear dest + inv-swz source + swz read).
static __device__ __forceinline__ void stage_chunk(
    const float* __restrict__ x, long Nb, float* ldsbuf,
    int w, int lane, long chByteBase)
{
#pragma unroll
    for (int i = 0; i < 8; ++i) {
        int p = ((w << 3) + i) * 1024 + lane * 16;     // byte offset in chunk
        int row = p >> 9;                              // atom row 0..63
        long src = chByteBase + (long)(p ^ ((row & 7) << 4));
        if (src > Nb - 16) src = Nb - 16;              // tail clamp (16B aligned)
        __builtin_amdgcn_global_load_lds(
            (const AS1 void*)((const char*)x + src),
            (AS3 void*)((char*)ldsbuf + (((w << 3) + i) * 1024)),
            16, 0, 0);
    }
}

// Fully fused, barrier-free kernel: per wave, per 16 atoms:
// stage(next) -> vmcnt -> MFMA(cur) -> xo reduce -> gather -> scan -> atomics.
__launch_bounds__(256)
__global__ void mlp_dipole_kernel(
    const float* __restrict__ x, const float* __restrict__ pos,
    const float* __restrict__ W1, const float* __restrict__ b1,
    const float* __restrict__ W2, const float* __restrict__ b2,
    const float* __restrict__ am, const int* __restrict__ z,
    const int* __restrict__ batch, float* __restrict__ ws,
    int N, int nChunks)
{
    __shared__ float lbuf[2][CHF];    // 2 x 32 KB double buffer (per-wave slices)

    const int tid  = threadIdx.x;
    const int lane = tid & 63;
    const int w    = tid >> 6;        // wave 0..3
    const int l15  = lane & 15;
    const int lg   = lane >> 4;

    float b1v[4], w2v[4];
#pragma unroll
    for (int ct = 0; ct < 4; ++ct) {
        b1v[ct] = b1[ct * 16 + l15];
        w2v[ct] = W2[ct * 16 + l15];
    }
    const float b2s = b2[0];

    // W1 fragments, register-resident for the whole kernel
    v8bf16 bf[4][4];
#pragma unroll
    for (int kt = 0; kt < 4; ++kt) {
#pragma unroll
        for (int ct = 0; ct < 4; ++ct) {
            const float* src = W1 + (ct * 16 + l15) * 128 + kt * 32 + lg * 8;
            v4f32 f0 = *reinterpret_cast<const v4f32*>(src);
            v4f32 f1 = *reinterpret_cast<const v4f32*>(src + 4);
            bf[kt][ct] = cvt8(f0, f1);
        }
    }

    const long Nb = (long)N * 512;    // bytes of x
    long ch = blockIdx.x;
    const long gstride = gridDim.x;

    if (ch < nChunks) stage_chunk(x, Nb, lbuf[0], w, lane, ch * 32768L);

    int cur = 0;
    while (ch < nChunks) {
        const long nxt = ch + gstride;
        const bool hasNxt = (nxt < nChunks);

        // 1. issue next chunk's stage, then retire current chunk's stages.
        //    vmcnt is per-wave and retires IN ISSUE ORDER: waiting down to the
        //    8 just-issued loads guarantees everything older (current stages,
        //    prev gathers, prev atomics) is complete. Last iteration issues
        //    nothing new -> must drain to 0.
        if (hasNxt) {
            stage_chunk(x, Nb, lbuf[cur ^ 1], w, lane, nxt * 32768L);
            asm volatile("s_waitcnt vmcnt(8)" ::: "memory");
        } else {
            asm volatile("s_waitcnt vmcnt(0)" ::: "memory");
        }

        // 2. MFMA on this wave's 16 rows of lbuf[cur] (swizzled reads, <=2-way)
        const float* rp = lbuf[cur];
        const int row   = w * 16 + l15;
        const int sw    = (row & 7) << 2;     // dword-index XOR
        const int rbase = row * 128;

        v4f32 acc[4];
#pragma unroll
        for (int ct = 0; ct < 4; ++ct) acc[ct] = (v4f32){0.f, 0.f, 0.f, 0.f};

#pragma unroll
        for (int kt = 0; kt < 4; ++kt) {
            const int c0 = kt * 32 + lg * 8;
            v4f32 f0 = *reinterpret_cast<const v4f32*>(rp + (rbase + ((c0    ) ^ sw)));
            v4f32 f1 = *reinterpret_cast<const v4f32*>(rp + (rbase + ((c0 + 4) ^ sw)));
            v8bf16 af = cvt8(f0, f1);
#pragma unroll
            for (int ct = 0; ct < 4; ++ct)
                acc[ct] = __builtin_amdgcn_mfma_f32_16x16x32_bf16(af, bf[kt][ct], acc[ct], 0, 0, 0);
        }

        // 3. xo = silu(acc+b1).w2 reduced over the 64 channels
        float part0 = 0.f, part1 = 0.f, part2 = 0.f, part3 = 0.f;
#pragma unroll
        for (int ct = 0; ct < 4; ++ct) {
            part0 += silu_f(acc[ct][0] + b1v[ct]) * w2v[ct];
            part1 += silu_f(acc[ct][1] + b1v[ct]) * w2v[ct];
            part2 += silu_f(acc[ct][2] + b1v[ct]) * w2v[ct];
            part3 += silu_f(acc[ct][3] + b1v[ct]) * w2v[ct];
        }
#pragma unroll
        for (int d = 1; d < 16; d <<= 1) {
            part0 += __shfl_xor(part0, d);
            part1 += __shfl_xor(part1, d);
            part2 += __shfl_xor(part2, d);
            part3 += __shfl_xor(part3, d);
        }
        const int srcl = (l15 >> 2) << 4;
        float t0 = __shfl(part0, srcl);
        float t1 = __shfl(part1, srcl);
        float t2 = __shfl(part2, srcl);
        float t3 = __shfl(part3, srcl);
        const int rr = lane & 3;
        float xo = ((rr == 0) ? t0 : (rr == 1) ? t1 : (rr == 2) ? t2 : t3) + b2s;

        // 4. dipole accumulation for this wave's 16 atoms (proven in round 2)
        if (lane < 16) {
            int a = (int)(ch * 64) + w * 16 + lane;
            bool valid = (a < N);
            int ac = valid ? a : N - 1;
            float sc = valid ? 1.0f : 0.0f;
            float px = pos[ac * 3 + 0];
            float py = pos[ac * 3 + 1];
            float pz = pos[ac * 3 + 2];
            int   bi = batch[ac];
            float m  = am[z[ac]];
            float v0 = sc * xo * px, v1 = sc * xo * py, v2 = sc * xo * pz, v3 = sc * xo;
            float v4 = sc * m  * px, v5 = sc * m  * py, v6 = sc * m  * pz, v7 = sc * m;

            int bprev = __shfl_up(bi, 1);
            bool head = (lane == 0) || (bi != bprev);
            unsigned long long hm = __ballot(head);
            unsigned long long below = hm & ((2ull << lane) - 1ull);
            int rs = 63 - __builtin_clzll(below);

#define SCAN_STEP(d)                                                            \
            {                                                                   \
                float u0 = __shfl_up(v0, d), u1 = __shfl_up(v1, d);             \
                float u2 = __shfl_up(v2, d), u3 = __shfl_up(v3, d);             \
                float u4 = __shfl_up(v4, d), u5 = __shfl_up(v5, d);             \
                float u6 = __shfl_up(v6, d), u7 = __shfl_up(v7, d);             \
                if (lane >= rs + d) {                                           \
                    v0 += u0; v1 += u1; v2 += u2; v3 += u3;                     \
                    v4 += u4; v5 += u5; v6 += u6; v7 += u7;                     \
                }                                                               \
            }
            SCAN_STEP(1)
            SCAN_STEP(2)
            SCAN_STEP(4)
            SCAN_STEP(8)
#undef SCAN_STEP

            bool tail = (lane == 15) || ((hm >> (lane + 1)) & 1ull);
            if (tail) {
                float* p = ws + (long)bi * 8;
                atomicAdd(p + 0, v0);
                atomicAdd(p + 1, v1);
                atomicAdd(p + 2, v2);
                atomicAdd(p + 3, v3);
                atomicAdd(p + 4, v4);
                atomicAdd(p + 5, v5);
                atomicAdd(p + 6, v6);
                atomicAdd(p + 7, v7);
            }
        }

        cur ^= 1;
        ch = nxt;
    }
}

__global__ void finalize_kernel(const float* __restrict__ ws, float* __restrict__ out, int B) {
    int b = blockIdx.x * blockDim.x + threadIdx.x;
    if (b >= B) return;
    const float* p = ws + (long)b * 8;
    float s1x = p[0], s1y = p[1], s1z = p[2], s2 = p[3];
    float pxs = p[4], pys = p[5], pzs = p[6], m = p[7];
    float inv = (m > 0.0f) ? (1.0f / m) : 1.0f;
    float vx = s1x - s2 * (pxs * inv);
    float vy = s1y - s2 * (pys * inv);
    float vz = s1z - s2 * (pzs * inv);
    out[b] = sqrtf(vx * vx + vy * vy + vz * vz);
}

extern "C" void kernel_launch(void* const* d_in, const int* in_sizes, int n_in,
                              void* d_out, int out_size, void* d_ws, size_t ws_size,
                              hipStream_t stream) {
    const float* x     = (const float*)d_in[0];
    const float* pos   = (const float*)d_in[1];
    const float* W1    = (const float*)d_in[2];
    const float* b1    = (const float*)d_in[3];
    const float* W2    = (const float*)d_in[4];
    const float* b2    = (const float*)d_in[5];
    const float* am    = (const float*)d_in[6];
    const int*   z     = (const int*)d_in[7];
    const int*   batch = (const int*)d_in[8];

    const int N = in_sizes[7];
    const int B = out_size;
    float* ws  = (float*)d_ws;       // [B][8] accumulators (1 MB, proven in R2)
    float* out = (float*)d_out;

    const int nChunks = (N + 63) / 64;

    int zn = B * 8;
    hipLaunchKernelGGL(zero_ws_kernel, dim3((zn + 255) / 256), dim3(256), 0, stream, ws, zn);

    int grid = nChunks < MAIN_GRID ? nChunks : MAIN_GRID;
    hipLaunchKernelGGL(mlp_dipole_kernel, dim3(grid), dim3(256), 0, stream,
                       x, pos, W1, b1, W2, b2, am, z, batch, ws, N, nChunks);

    hipLaunchKernelGGL(finalize_kernel, dim3((B + 255) / 256), dim3(256), 0, stream, ws, out, B);
}

// Round 5
// 119.407 us; speedup vs baseline: 1.1153x; 1.1153x over previous
//
#include <hip/hip_runtime.h>
#include <hip/hip_bf16.h>

typedef __bf16 v8bf16 __attribute__((ext_vector_type(8)));
typedef float  v4f32  __attribute__((ext_vector_type(4)));

#define AS1 __attribute__((address_space(1)))
#define AS3 __attribute__((address_space(3)))

#define CHF 8192          // floats per 64-atom chunk (64*128), 32 KB
#define MAIN_GRID 512     // 2 blocks/CU resident (LDS-limited)

static __device__ __forceinline__ float silu_f(float v) {
    return v / (1.0f + __expf(-v));
}

static __device__ __forceinline__ v8bf16 cvt8(v4f32 f0, v4f32 f1) {
    v8bf16 t;
    t[0] = (__bf16)f0[0]; t[1] = (__bf16)f0[1]; t[2] = (__bf16)f0[2]; t[3] = (__bf16)f0[3];
    t[4] = (__bf16)f1[0]; t[5] = (__bf16)f1[1]; t[6] = (__bf16)f1[2]; t[7] = (__bf16)f1[3];
    return t;
}

__global__ void zero_ws_kernel(float* __restrict__ ws, int n) {
    int i = blockIdx.x * blockDim.x + threadIdx.x;
    if (i < n) ws[i] = 0.0f;
}

// Stage one 64-atom chunk (32 KB of x) into LDS via global_load_lds.
// Each wave stages ONLY its own 16 rows (w*16 .. w*16+15) and later reads
// ONLY those rows -> waves are fully independent, no barriers in the loop.
// LDS dest linear; global SOURCE carries the inverse of the read-side XOR
// swizzle (rule #21: linear dest + inv-swz source + swz read).
static __device__ __forceinline__ void stage_chunk(
    const float* __restrict__ x, long Nb, float* ldsbuf,
    int w, int lane, long chByteBase)
{
#pragma unroll
    for (int i = 0; i < 8; ++i) {
        int p = ((w << 3) + i) * 1024 + lane * 16;     // byte offset in chunk
        int row = p >> 9;                              // atom row 0..63
        long src = chByteBase + (long)(p ^ ((row & 7) << 4));
        if (src > Nb - 16) src = Nb - 16;              // tail clamp (16B aligned)
        __builtin_amdgcn_global_load_lds(
            (const AS1 void*)((const char*)x + src),
            (AS3 void*)((char*)ldsbuf + (((w << 3) + i) * 1024)),
            16, 0, 0);
    }
}

// Fused barrier-free kernel with depth-1 software pipeline on BOTH the
// x-stage (global_load_lds) and the metadata gathers (pos/batch/z).
// Invariant: no wait in the steady-state loop ever forces retirement of the
// just-issued stage(c+1): the top-of-loop vmcnt(8) retires only ops issued
// a full iteration earlier; metadata is consumed from registers prefetched
// last iteration; am[] is read from LDS (lgkmcnt, not vmcnt).
__launch_bounds__(256)
__global__ void mlp_dipole_kernel(
    const float* __restrict__ x, const float* __restrict__ pos,
    const float* __restrict__ W1, const float* __restrict__ b1,
    const float* __restrict__ W2, const float* __restrict__ b2,
    const float* __restrict__ am, const int* __restrict__ z,
    const int* __restrict__ batch, float* __restrict__ ws,
    int N, int nChunks, int amN)
{
    __shared__ float lbuf[2][CHF];    // 2 x 32 KB double buffer (per-wave slices)
    __shared__ float amt[128];        // atomic-mass table (epilogue stays VMEM-free)

    const int tid  = threadIdx.x;
    const int lane = tid & 63;
    const int w    = tid >> 6;        // wave 0..3
    const int l15  = lane & 15;
    const int lg   = lane >> 4;

    if (tid < amN) amt[tid] = am[tid];

    float b1v[4], w2v[4];
#pragma unroll
    for (int ct = 0; ct < 4; ++ct) {
        b1v[ct] = b1[ct * 16 + l15];
        w2v[ct] = W2[ct * 16 + l15];
    }
    const float b2s = b2[0];

    // W1 fragments, register-resident for the whole kernel
    v8bf16 bf[4][4];
#pragma unroll
    for (int kt = 0; kt < 4; ++kt) {
#pragma unroll
        for (int ct = 0; ct < 4; ++ct) {
            const float* src = W1 + (ct * 16 + l15) * 128 + kt * 32 + lg * 8;
            v4f32 f0 = *reinterpret_cast<const v4f32*>(src);
            v4f32 f1 = *reinterpret_cast<const v4f32*>(src + 4);
            bf[kt][ct] = cvt8(f0, f1);
        }
    }

    // amt[] must be visible to all 4 waves before any epilogue; this is the
    // ONLY barrier, before any stages are in flight (drain here is harmless).
    __syncthreads();

    const long Nb = (long)N * 512;    // bytes of x
    long ch = blockIdx.x;
    const long gstride = gridDim.x;

    // ---- prologue: stage chunk0 + gather chunk0 metadata ----
    if (ch < nChunks) stage_chunk(x, Nb, lbuf[0], w, lane, ch * 32768L);

    float gpx = 0.f, gpy = 0.f, gpz = 0.f;
    int gbi = 0, gzi = 0;
    if (lane < 16 && ch < nChunks) {
        int a = (int)(ch * 64) + w * 16 + lane;
        int ac = (a < N) ? a : N - 1;
        gpx = pos[ac * 3 + 0]; gpy = pos[ac * 3 + 1]; gpz = pos[ac * 3 + 2];
        gbi = batch[ac]; gzi = z[ac];
    }

    int cur = 0;
    while (ch < nChunks) {
        const long nxt = ch + gstride;
        const bool hasNxt = (nxt < nChunks);

        // 1. issue next chunk's stage; retire current chunk's stages + current
        //    metadata gathers (all issued >= 1 iteration ago -> near-free wait).
        //    Final iteration issues nothing new -> drain to 0 (R3 bug fix).
        if (hasNxt) {
            stage_chunk(x, Nb, lbuf[cur ^ 1], w, lane, nxt * 32768L);
            asm volatile("s_waitcnt vmcnt(8)" ::: "memory");
        } else {
            asm volatile("s_waitcnt vmcnt(0)" ::: "memory");
        }

        // 2. MFMA on this wave's 16 rows of lbuf[cur] (swizzled reads, <=2-way)
        const float* rp = lbuf[cur];
        const int row   = w * 16 + l15;
        const int sw    = (row & 7) << 2;     // dword-index XOR
        const int rbase = row * 128;

        v4f32 acc[4];
#pragma unroll
        for (int ct = 0; ct < 4; ++ct) acc[ct] = (v4f32){0.f, 0.f, 0.f, 0.f};

#pragma unroll
        for (int kt = 0; kt < 4; ++kt) {
            const int c0 = kt * 32 + lg * 8;
            v4f32 f0 = *reinterpret_cast<const v4f32*>(rp + (rbase + ((c0    ) ^ sw)));
            v4f32 f1 = *reinterpret_cast<const v4f32*>(rp + (rbase + ((c0 + 4) ^ sw)));
            v8bf16 af = cvt8(f0, f1);
#pragma unroll
            for (int ct = 0; ct < 4; ++ct)
                acc[ct] = __builtin_amdgcn_mfma_f32_16x16x32_bf16(af, bf[kt][ct], acc[ct], 0, 0, 0);
        }

        // 3. prefetch NEXT chunk's metadata (issued after stage(c+1), consumed
        //    next iteration after the vmcnt(8) that retires them -> no drain).
        float npx = 0.f, npy = 0.f, npz = 0.f;
        int nbi = 0, nzi = 0;
        if (lane < 16 && hasNxt) {
            int a = (int)(nxt * 64) + w * 16 + lane;
            int ac = (a < N) ? a : N - 1;
            npx = pos[ac * 3 + 0]; npy = pos[ac * 3 + 1]; npz = pos[ac * 3 + 2];
            nbi = batch[ac]; nzi = z[ac];
        }

        // 4. xo = silu(acc+b1).w2 reduced over the 64 channels
        float part0 = 0.f, part1 = 0.f, part2 = 0.f, part3 = 0.f;
#pragma unroll
        for (int ct = 0; ct < 4; ++ct) {
            part0 += silu_f(acc[ct][0] + b1v[ct]) * w2v[ct];
            part1 += silu_f(acc[ct][1] + b1v[ct]) * w2v[ct];
            part2 += silu_f(acc[ct][2] + b1v[ct]) * w2v[ct];
            part3 += silu_f(acc[ct][3] + b1v[ct]) * w2v[ct];
        }
#pragma unroll
        for (int d = 1; d < 16; d <<= 1) {
            part0 += __shfl_xor(part0, d);
            part1 += __shfl_xor(part1, d);
            part2 += __shfl_xor(part2, d);
            part3 += __shfl_xor(part3, d);
        }
        const int srcl = (l15 >> 2) << 4;
        float t0 = __shfl(part0, srcl);
        float t1 = __shfl(part1, srcl);
        float t2 = __shfl(part2, srcl);
        float t3 = __shfl(part3, srcl);
        const int rr = lane & 3;
        float xo = ((rr == 0) ? t0 : (rr == 1) ? t1 : (rr == 2) ? t2 : t3) + b2s;

        // 5. dipole accumulation for this wave's 16 atoms (registers + LDS only)
        if (lane < 16) {
            int a = (int)(ch * 64) + w * 16 + lane;
            bool valid = (a < N);
            float sc = valid ? 1.0f : 0.0f;
            float px = gpx, py = gpy, pz = gpz;
            int   bi = gbi;
            float m  = amt[gzi];
            float v0 = sc * xo * px, v1 = sc * xo * py, v2 = sc * xo * pz, v3 = sc * xo;
            float v4 = sc * m  * px, v5 = sc * m  * py, v6 = sc * m  * pz, v7 = sc * m;

            int bprev = __shfl_up(bi, 1);
            bool head = (lane == 0) || (bi != bprev);
            unsigned long long hm = __ballot(head);
            unsigned long long below = hm & ((2ull << lane) - 1ull);
            int rs = 63 - __builtin_clzll(below);

#define SCAN_STEP(d)                                                            \
            {                                                                   \
                float u0 = __shfl_up(v0, d), u1 = __shfl_up(v1, d);             \
                float u2 = __shfl_up(v2, d), u3 = __shfl_up(v3, d);             \
                float u4 = __shfl_up(v4, d), u5 = __shfl_up(v5, d);             \
                float u6 = __shfl_up(v6, d), u7 = __shfl_up(v7, d);             \
                if (lane >= rs + d) {                                           \
                    v0 += u0; v1 += u1; v2 += u2; v3 += u3;                     \
                    v4 += u4; v5 += u5; v6 += u6; v7 += u7;                     \
                }                                                               \
            }
            SCAN_STEP(1)
            SCAN_STEP(2)
            SCAN_STEP(4)
            SCAN_STEP(8)
#undef SCAN_STEP

            bool tail = (lane == 15) || ((hm >> (lane + 1)) & 1ull);
            if (tail) {
                float* p = ws + (long)bi * 8;
                atomicAdd(p + 0, v0);
                atomicAdd(p + 1, v1);
                atomicAdd(p + 2, v2);
                atomicAdd(p + 3, v3);
                atomicAdd(p + 4, v4);
                atomicAdd(p + 5, v5);
                atomicAdd(p + 6, v6);
                atomicAdd(p + 7, v7);
            }
        }

        gpx = npx; gpy = npy; gpz = npz; gbi = nbi; gzi = nzi;
        cur ^= 1;
        ch = nxt;
    }
}

__global__ void finalize_kernel(const float* __restrict__ ws, float* __restrict__ out, int B) {
    int b = blockIdx.x * blockDim.x + threadIdx.x;
    if (b >= B) return;
    const float* p = ws + (long)b * 8;
    float s1x = p[0], s1y = p[1], s1z = p[2], s2 = p[3];
    float pxs = p[4], pys = p[5], pzs = p[6], m = p[7];
    float inv = (m > 0.0f) ? (1.0f / m) : 1.0f;
    float vx = s1x - s2 * (pxs * inv);
    float vy = s1y - s2 * (pys * inv);
    float vz = s1z - s2 * (pzs * inv);
    out[b] = sqrtf(vx * vx + vy * vy + vz * vz);
}

extern "C" void kernel_launch(void* const* d_in, const int* in_sizes, int n_in,
                              void* d_out, int out_size, void* d_ws, size_t ws_size,
                              hipStream_t stream) {
    const float* x     = (const float*)d_in[0];
    const float* pos   = (const float*)d_in[1];
    const float* W1    = (const float*)d_in[2];
    const float* b1    = (const float*)d_in[3];
    const float* W2    = (const float*)d_in[4];
    const float* b2    = (const float*)d_in[5];
    const float* am    = (const float*)d_in[6];
    const int*   z     = (const int*)d_in[7];
    const int*   batch = (const int*)d_in[8];

    const int N   = in_sizes[7];
    const int amN = in_sizes[6] < 128 ? in_sizes[6] : 128;
    const int B   = out_size;
    float* ws  = (float*)d_ws;       // [B][8] accumulators
    float* out = (float*)d_out;

    const int nChunks = (N + 63) / 64;

    int zn = B * 8;
    hipLaunchKernelGGL(zero_ws_kernel, dim3((zn + 255) / 256), dim3(256), 0, stream, ws, zn);

    int grid = nChunks < MAIN_GRID ? nChunks : MAIN_GRID;
    hipLaunchKernelGGL(mlp_dipole_kernel, dim3(grid), dim3(256), 0, stream,
                       x, pos, W1, b1, W2, b2, am, z, batch, ws, N, nChunks, amN);

    hipLaunchKernelGGL(finalize_kernel, dim3((B + 255) / 256), dim3(256), 0, stream, ws, out, B);
}